// Round 6
// baseline (99.827 us; speedup 1.0000x reference)
//
#include <hip/hip_runtime.h>

// reference: out[b,s,:] = emb_weight[ clamp(lookup_table[input_ids[b,s]], 0, 31999) ]
// shapes: input_ids [16,4096] i32, lookup_table [128000] i32, emb_weight [32000,768] f32
// out [16,4096,768] f32
//
// R5 post-mortem: 8-pass re-scan regressed (75us) - per-block overhead x8.
// This round: counting-sort tokens by id-bucket (id>>5, 1000 buckets) in 4
// tiny kernels, then ONE gather pass in sorted order -> row duplicates are
// <=96KB apart in the read stream (L2 hits), reads become near-sequential.
// Predicted: HBM reads 201MB -> ~105MB, dur 63 -> ~50-56us.

constexpr int EMB_DIM  = 768;
constexpr int ROW_F4   = EMB_DIM / 4;     // 192 float4 per row
constexpr int VOCAB    = 32000;
constexpr int NTOK     = 16 * 4096;       // 65536
constexpr int BSHIFT   = 5;               // bucket = id >> 5  (32 rows = 96KB)
constexpr int NBUCKET  = VOCAB >> BSHIFT; // 1000
constexpr int SCANSZ   = 1024;            // padded scan size

typedef float vfloat4 __attribute__((ext_vector_type(4)));

__device__ __forceinline__ void store_nt_wa(vfloat4* p, vfloat4 v) {
    asm volatile("global_store_dwordx4 %0, %1, off sc0 sc1 nt"
                 :: "v"(p), "v"(v) : "memory");
}

// --- sort pipeline -----------------------------------------------------------

__global__ __launch_bounds__(1024) void zero_hist(int* __restrict__ hist) {
    hist[threadIdx.x] = 0;                       // <<<1,1024>>>, SCANSZ ints
}

__global__ __launch_bounds__(256) void map_hist(
    const int* __restrict__ input_ids,
    const int* __restrict__ lookup,
    int* __restrict__ mapped,
    int* __restrict__ hist, int ntok)
{
    int t = blockIdx.x * blockDim.x + threadIdx.x;   // grid exactly covers ntok
    if (t >= ntok) return;
    int id = lookup[input_ids[t]];
    id = min(max(id, 0), VOCAB - 1);
    mapped[t] = id;
    atomicAdd(&hist[id >> BSHIFT], 1);
}

__global__ __launch_bounds__(1024) void scan_excl(int* __restrict__ hist) {
    __shared__ int tmp[SCANSZ];
    int i = threadIdx.x;
    int v = hist[i];
    tmp[i] = v;
    __syncthreads();
    for (int off = 1; off < SCANSZ; off <<= 1) {
        int add = (i >= off) ? tmp[i - off] : 0;
        __syncthreads();
        tmp[i] += add;
        __syncthreads();
    }
    hist[i] = tmp[i] - v;                        // exclusive prefix (= running offsets)
}

__global__ __launch_bounds__(256) void scatter(
    const int* __restrict__ mapped,
    int* __restrict__ hist,                      // running offsets (consumed)
    int* __restrict__ sortedTok,
    int* __restrict__ sortedId, int ntok)
{
    int t = blockIdx.x * blockDim.x + threadIdx.x;
    if (t >= ntok) return;
    int id  = mapped[t];
    int pos = atomicAdd(&hist[id >> BSHIFT], 1);
    sortedTok[pos] = t;
    sortedId[pos]  = id;
}

// --- gather in sorted order --------------------------------------------------

__global__ __launch_bounds__(256) void token_emb_gather_sorted(
    const int*     __restrict__ sortedTok,
    const int*     __restrict__ sortedId,
    const vfloat4* __restrict__ emb,
    vfloat4*       __restrict__ out, int ntok)
{
    int k = blockIdx.x * 4 + threadIdx.y;        // one wave per sorted slot
    if (k >= ntok) return;

    int token = sortedTok[k];                    // wave-uniform -> broadcast
    int id    = sortedId[k];

    const vfloat4* __restrict__ src = emb + (size_t)id    * ROW_F4;
    vfloat4*       __restrict__ dst = out + (size_t)token * ROW_F4;

    int lane = threadIdx.x;
    vfloat4 v0 = src[lane];
    vfloat4 v1 = src[lane + 64];
    vfloat4 v2 = src[lane + 128];
    store_nt_wa(dst + lane,       v0);
    store_nt_wa(dst + lane + 64,  v1);
    store_nt_wa(dst + lane + 128, v2);
}

// --- fallback (R4 baseline) --------------------------------------------------

__global__ __launch_bounds__(256) void token_emb_gather_plain(
    const int*     __restrict__ input_ids,
    const int*     __restrict__ lookup,
    const vfloat4* __restrict__ emb,
    vfloat4*       __restrict__ out, int ntok)
{
    int token = blockIdx.x * 4 + threadIdx.y;
    if (token >= ntok) return;
    int id = lookup[input_ids[token]];
    id = min(max(id, 0), VOCAB - 1);
    const vfloat4* __restrict__ src = emb + (size_t)id    * ROW_F4;
    vfloat4*       __restrict__ dst = out + (size_t)token * ROW_F4;
    int lane = threadIdx.x;
    vfloat4 v0 = src[lane];
    vfloat4 v1 = src[lane + 64];
    vfloat4 v2 = src[lane + 128];
    store_nt_wa(dst + lane,       v0);
    store_nt_wa(dst + lane + 64,  v1);
    store_nt_wa(dst + lane + 128, v2);
}

extern "C" void kernel_launch(void* const* d_in, const int* in_sizes, int n_in,
                              void* d_out, int out_size, void* d_ws, size_t ws_size,
                              hipStream_t stream)
{
    const int*     input_ids = (const int*)d_in[0];
    const int*     lookup    = (const int*)d_in[1];
    const vfloat4* emb       = (const vfloat4*)d_in[2];
    vfloat4*       out       = (vfloat4*)d_out;

    int ntok = in_sizes[0];                      // 65536

    // ws layout (ints): mapped[ntok] | sortedTok[ntok] | sortedId[ntok] | hist[SCANSZ]
    size_t need = (size_t)(3 * ntok + SCANSZ) * sizeof(int);
    dim3 gblock(64, 4);
    dim3 ggrid((ntok + 3) / 4);

    if (ws_size < need) {  // scratch too small: R4 baseline (63us)
        token_emb_gather_plain<<<ggrid, gblock, 0, stream>>>(input_ids, lookup, emb, out, ntok);
        return;
    }

    int* mapped    = (int*)d_ws;
    int* sortedTok = mapped + ntok;
    int* sortedId  = sortedTok + ntok;
    int* hist      = sortedId + ntok;

    int nthread_blocks = (ntok + 255) / 256;     // 256

    zero_hist<<<1, SCANSZ, 0, stream>>>(hist);
    map_hist<<<nthread_blocks, 256, 0, stream>>>(input_ids, lookup, mapped, hist, ntok);
    scan_excl<<<1, SCANSZ, 0, stream>>>(hist);
    scatter<<<nthread_blocks, 256, 0, stream>>>(mapped, hist, sortedTok, sortedId, ntok);
    token_emb_gather_sorted<<<ggrid, gblock, 0, stream>>>(sortedTok, sortedId, emb, out, ntok);
}

// Round 7
// 63.058 us; speedup vs baseline: 1.5831x; 1.5831x over previous
//
#include <hip/hip_runtime.h>

// reference: out[b,s,:] = emb_weight[ clamp(lookup_table[input_ids[b,s]], 0, 31999) ]
// shapes: input_ids [16,4096] i32, lookup_table [128000] i32, emb_weight [32000,768] f32
// out [16,4096,768] f32
//
// FINAL (restored R4 winner, 63.07 us = 6.40 TB/s on 403 MB):
//  - one 64-lane wave per token; wave-uniform id load broadcasts; 16B/lane
//    fully-coalesced row copy (3x global_load_dwordx4 + 3x store).
//  - sequential write stream (token order) is the dominant locality asset.
// Ruled out by experiment:
//  - NT / sc0 sc1 store flags: null (MALL allocation unaffected)      [R3/R4]
//  - 8-pass vocab-chunk re-scan: +12 us block overhead                [R5]
//  - counting-sort by id: +37 us (scattered writes + sort pipeline)   [R6]
// Reuse is uncapturable: harness's ~805 MB fill inside every replay flushes
// the 256 MB MALL; within-replay reuse distance ~ capacity. 403 MB is the
// minimal byte count => 6.4 TB/s mixed = roofline.

constexpr int EMB_DIM   = 768;            // floats per row
constexpr int ROW_F4    = EMB_DIM / 4;    // 192 float4 per row
constexpr int VOCAB     = 32000;

typedef float vfloat4 __attribute__((ext_vector_type(4)));

__device__ __forceinline__ void store_nt_wa(vfloat4* p, vfloat4 v) {
    asm volatile("global_store_dwordx4 %0, %1, off sc0 sc1 nt"
                 :: "v"(p), "v"(v) : "memory");
}

__global__ __launch_bounds__(256) void token_emb_gather(
    const int*     __restrict__ input_ids,
    const int*     __restrict__ lookup,
    const vfloat4* __restrict__ emb,   // [VOCAB][192]
    vfloat4*       __restrict__ out,   // [ntok][192]
    int ntok)
{
    // blockDim = (64, 4): one wave per token, 4 tokens per block
    int token = blockIdx.x * 4 + threadIdx.y;
    if (token >= ntok) return;

    int id = lookup[input_ids[token]];          // wave-uniform -> broadcast
    id = min(max(id, 0), VOCAB - 1);            // clamp as in reference

    const vfloat4* __restrict__ src = emb + (size_t)id    * ROW_F4;
    vfloat4*       __restrict__ dst = out + (size_t)token * ROW_F4;

    int lane = threadIdx.x;                     // 0..63

    vfloat4 v0 = src[lane];
    vfloat4 v1 = src[lane + 64];
    vfloat4 v2 = src[lane + 128];
    store_nt_wa(dst + lane,       v0);
    store_nt_wa(dst + lane + 64,  v1);
    store_nt_wa(dst + lane + 128, v2);
}

extern "C" void kernel_launch(void* const* d_in, const int* in_sizes, int n_in,
                              void* d_out, int out_size, void* d_ws, size_t ws_size,
                              hipStream_t stream)
{
    const int*     input_ids = (const int*)d_in[0];
    const int*     lookup    = (const int*)d_in[1];
    const vfloat4* emb       = (const vfloat4*)d_in[2];
    vfloat4*       out       = (vfloat4*)d_out;

    int ntok = in_sizes[0];                     // 16*4096 = 65536

    dim3 block(64, 4);
    dim3 grid((ntok + 3) / 4);
    token_emb_gather<<<grid, block, 0, stream>>>(input_ids, lookup, emb, out, ntok);
}